// Round 4
// baseline (580.858 us; speedup 1.0000x reference)
//
#include <hip/hip_runtime.h>

// ---- problem constants ----
#define SRAD 3
#define TRAD 1
#define Hdim 256
#define Wdim 256
#define Tdim 32
#define CS (Hdim*Wdim*Tdim)

// ---- tiling ----
#define TH 8
#define TW 16
#define TT 8
#define HS (TH + 2*SRAD)      // 14
#define WS (TW + 2*SRAD)      // 22
#define TSZ (TT + 2*TRAD)     // 10
#define NPX (HS*WS*TSZ)       // 3080
#define NTHREADS 1024
#define NSUB 4

// LDS (dword offsets): AG [NPX][4] = g0g1,g2g3,g4g5,g6g7 (fp16 pairs, sigma-scaled)
//                      EVN[NPX][4] = e0v0,e1v1,e2v2,n0n1 (fp16 pairs)
//                      X  [NPX][1] = g8n2
#define EV_OFF (4*NPX)
#define X_OFF  (8*NPX)
#define SMEM_BYTES (9*NPX*4)   // 110,880 B (1 block/CU in 160 KiB pool)

typedef _Float16 half2_t __attribute__((ext_vector_type(2)));

#if defined(__has_builtin)
#if __has_builtin(__builtin_amdgcn_fdot2)
#define HAVE_FDOT2 1
#else
#define HAVE_FDOT2 0
#endif
#else
#define HAVE_FDOT2 0
#endif

static __device__ __forceinline__ unsigned pack_h2(float a, float b) {
    return __builtin_bit_cast(unsigned, __builtin_amdgcn_cvt_pkrtz(a, b));
}
static __device__ __forceinline__ half2_t h2(unsigned u) {
    return __builtin_bit_cast(half2_t, u);
}
static __device__ __forceinline__ float dacc(unsigned y, unsigned x, float acc) {
    half2_t d = h2(y) - h2(x);
#if HAVE_FDOT2
    return __builtin_amdgcn_fdot2(d, d, acc, false);
#else
    float a = (float)d.x, b = (float)d.y;
    return __builtin_fmaf(a, a, __builtin_fmaf(b, b, acc));
#endif
}
// only low half (g8) contributes; high half carries n2
static __device__ __forceinline__ float dacc_lo(unsigned y, unsigned x, float acc) {
    half2_t d = h2(y) - h2(x);
    half2_t dm = h2(__builtin_bit_cast(unsigned, d) & 0xFFFFu);
#if HAVE_FDOT2
    return __builtin_amdgcn_fdot2(dm, dm, acc, false);
#else
    float a = (float)dm.x;
    return __builtin_fmaf(a, a, acc);
#endif
}

__global__ __launch_bounds__(NTHREADS, 4) void statden_kernel(
    const float* __restrict__ noisy, const float* __restrict__ guidance,
    const float* __restrict__ est, const float* __restrict__ var,
    const float* __restrict__ sigma_inv, float* __restrict__ out)
{
    extern __shared__ unsigned char smem[];
    unsigned* agP = (unsigned*)smem;
    unsigned* evP = agP + EV_OFF;
    unsigned* xP  = agP + X_OFF;

    const int tid = threadIdx.x;
    const int pix = tid & 255;
    const int sub = tid >> 8;            // 4-way (dh,dw)-offset split
    const int h0 = blockIdx.y * TH;
    const int w0 = blockIdx.x * TW;
    const int t0 = blockIdx.z * TT;

    float sq[9];
    #pragma unroll
    for (int c = 0; c < 9; ++c) sq[c] = sqrtf(sigma_inv[c]);

    // ---- stage halo (zero-fill OOB == reference zero padding) ----
    for (int p = tid; p < NPX; p += NTHREADS) {
        int pt = p % TSZ;
        int q  = p / TSZ;
        int pw = q % WS;
        int ph = q / WS;
        int h = h0 - SRAD + ph;
        int w = w0 - SRAD + pw;
        int t = t0 - TRAD + pt;
        bool ok = ((unsigned)h < (unsigned)Hdim) && ((unsigned)w < (unsigned)Wdim)
               && ((unsigned)t < (unsigned)Tdim);
        int base = (h * Wdim + w) * Tdim + t;

        float g[9];
        #pragma unroll
        for (int c = 0; c < 9; ++c) g[c] = ok ? guidance[c*CS + base] * sq[c] : 0.f;
        float e0 = ok ? est[0*CS + base] : 0.f;
        float e1 = ok ? est[1*CS + base] : 0.f;
        float e2 = ok ? est[2*CS + base] : 0.f;
        float v0 = ok ? var[0*CS + base] : 0.f;
        float v1 = ok ? var[1*CS + base] : 0.f;
        float v2 = ok ? var[2*CS + base] : 0.f;
        float n0 = ok ? noisy[0*CS + base] : 0.f;
        float n1 = ok ? noisy[1*CS + base] : 0.f;
        float n2 = ok ? noisy[2*CS + base] : 0.f;

        uint4 ag;
        ag.x = pack_h2(g[0], g[1]); ag.y = pack_h2(g[2], g[3]);
        ag.z = pack_h2(g[4], g[5]); ag.w = pack_h2(g[6], g[7]);
        *(uint4*)(agP + 4*p) = ag;
        uint4 ev;
        ev.x = pack_h2(e0, v0); ev.y = pack_h2(e1, v1);
        ev.z = pack_h2(e2, v2); ev.w = pack_h2(n0, n1);
        *(uint4*)(evP + 4*p) = ev;
        xP[p] = pack_h2(g[8], n2);
    }
    __syncthreads();

    // ---- per-thread output column: 4 consecutive t outputs ----
    const int tfh = pix & 1;
    const int ww  = (pix >> 1) & 15;
    const int hh  = pix >> 5;
    const int col = ((hh + SRAD) * WS + (ww + SRAD)) * TSZ + 4 * tfh;

    // center window (outputs j at window t-pos j+1)
    unsigned agx[4][4], gx8[4];
    half2_t  cxm[4][3];          // (-e_c, +v_c) center, bit-exact sign flip
    {
        const uint4* A4 = (const uint4*)(agP + 4*col);
        const uint4* E4 = (const uint4*)(evP + 4*col);
        const uint2* X2 = (const uint2*)(xP + col);
        uint4 cag[6], cev[6];
        #pragma unroll
        for (int i = 0; i < 6; ++i) { cag[i] = A4[i]; cev[i] = E4[i]; }
        uint2 x0 = X2[0], x1 = X2[1], x2 = X2[2];
        unsigned cxd[6] = {x0.x, x0.y, x1.x, x1.y, x2.x, x2.y};
        #pragma unroll
        for (int j = 0; j < 4; ++j) {
            const int tp = j + 1;
            agx[j][0] = cag[tp].x; agx[j][1] = cag[tp].y;
            agx[j][2] = cag[tp].z; agx[j][3] = cag[tp].w;
            gx8[j] = cxd[tp];
            cxm[j][0] = h2(cev[tp].x ^ 0x8000u);
            cxm[j][1] = h2(cev[tp].y ^ 0x8000u);
            cxm[j][2] = h2(cev[tp].z ^ 0x8000u);
        }
    }

    const _Float16 G2h = (_Float16)(2.9146f * 2.9146f);

    float nm[3][4] = {{0.f,0.f,0.f,0.f},{0.f,0.f,0.f,0.f},{0.f,0.f,0.f,0.f}};
    float den[4]   = {0.f,0.f,0.f,0.f};

    #pragma unroll 1
    for (int idx = sub; idx < 49; idx += NSUB) {
        const int dhp = idx / 7;               // 0..6
        const int dwp = idx - dhp * 7;         // 0..6
        const int pxo = col + (dhp - SRAD) * (WS * TSZ) + (dwp - SRAD) * TSZ;

        // phase 1: guidance -> wj[j][dt]
        uint4 ag[6];
        {
            const uint4* A4 = (const uint4*)(agP + 4*pxo);
            #pragma unroll
            for (int i = 0; i < 6; ++i) ag[i] = A4[i];
        }
        unsigned xd[6];
        {
            const uint2* X2 = (const uint2*)(xP + pxo);
            uint2 x0 = X2[0], x1 = X2[1], x2 = X2[2];
            xd[0]=x0.x; xd[1]=x0.y; xd[2]=x1.x; xd[3]=x1.y; xd[4]=x2.x; xd[5]=x2.y;
        }
        float wj[4][3];
        #pragma unroll
        for (int j = 0; j < 4; ++j) {
            #pragma unroll
            for (int dt = 0; dt < 3; ++dt) {
                const int tp = j + dt;
                float dist = dacc(ag[tp].x, agx[j][0], 0.f);
                dist = dacc(ag[tp].y, agx[j][1], dist);
                dist = dacc(ag[tp].z, agx[j][2], dist);
                dist = dacc(ag[tp].w, agx[j][3], dist);
                dist = dacc_lo(xd[tp], gx8[j], dist);
                wj[j][dt] = __expf(-dist);
            }
        }

        // phase 2a: t-test membership gates wj in place
        uint4 ev[6];
        {
            const uint4* E4 = (const uint4*)(evP + 4*pxo);
            #pragma unroll
            for (int i = 0; i < 6; ++i) ev[i] = E4[i];
        }
        #pragma unroll
        for (int j = 0; j < 4; ++j) {
            #pragma unroll
            for (int dt = 0; dt < 3; ++dt) {
                const int tp = j + dt;
                half2_t s0 = h2(ev[tp].x) + cxm[j][0];   // (de0, vs0)
                half2_t s1 = h2(ev[tp].y) + cxm[j][1];
                half2_t s2 = h2(ev[tp].z) + cxm[j][2];
                _Float16 m0 = __builtin_fmaf16(-s0.x, s0.x, G2h * s0.y);
                _Float16 m1 = __builtin_fmaf16(-s1.x, s1.x, G2h * s1.y);
                _Float16 m2 = __builtin_fmaf16(-s2.x, s2.x, G2h * s2.y);
                bool member = (m0 >= (_Float16)0) && (m1 >= (_Float16)0) && (m2 >= (_Float16)0);
                wj[j][dt] = member ? wj[j][dt] : 0.f;
            }
        }

        // phase 2b: accumulate
        float n0f[6], n1f[6], n2f[6];
        #pragma unroll
        for (int tp = 0; tp < 6; ++tp) {
            half2_t nh = h2(ev[tp].w);
            n0f[tp] = (float)nh.x; n1f[tp] = (float)nh.y;
            n2f[tp] = (float)h2(xd[tp]).y;
        }
        #pragma unroll
        for (int j = 0; j < 4; ++j) {
            #pragma unroll
            for (int dt = 0; dt < 3; ++dt) {
                const int tp = j + dt;
                const float wgt = wj[j][dt];
                nm[0][j] = __builtin_fmaf(wgt, n0f[tp], nm[0][j]);
                nm[1][j] = __builtin_fmaf(wgt, n1f[tp], nm[1][j]);
                nm[2][j] = __builtin_fmaf(wgt, n2f[tp], nm[2][j]);
                den[j] += wgt;
            }
        }
    }

    // ---- combine the 4 offset-split partials via LDS (swizzled, conflict-lite) ----
    float vals[16];
    #pragma unroll
    for (int c = 0; c < 3; ++c)
        #pragma unroll
        for (int j = 0; j < 4; ++j) vals[c*4 + j] = nm[c][j];
    #pragma unroll
    for (int j = 0; j < 4; ++j) vals[12 + j] = den[j];

    __syncthreads();
    float* red = (float*)smem;   // 3 * 256 * 16 * 4 B = 48 KB, reuse staged region
    if (sub != 0) {
        const int base = ((sub - 1) * 256 + pix) * 16;
        #pragma unroll
        for (int q = 0; q < 4; ++q) {
            float4 v;
            v.x = vals[4*q + 0]; v.y = vals[4*q + 1];
            v.z = vals[4*q + 2]; v.w = vals[4*q + 3];
            *(float4*)(red + base + 4 * (q ^ (pix & 3))) = v;
        }
    }
    __syncthreads();
    if (sub == 0) {
        #pragma unroll
        for (int s = 0; s < 3; ++s) {
            const int base = (s * 256 + pix) * 16;
            #pragma unroll
            for (int q = 0; q < 4; ++q) {
                float4 v = *(const float4*)(red + base + 4 * (q ^ (pix & 3)));
                vals[4*q + 0] += v.x; vals[4*q + 1] += v.y;
                vals[4*q + 2] += v.z; vals[4*q + 3] += v.w;
            }
        }
        float inv[4];
        #pragma unroll
        for (int j = 0; j < 4; ++j) inv[j] = 1.0f / (vals[12 + j] + 1e-10f);

        const int hG = h0 + hh, wG = w0 + ww;
        const int ob = (hG * Wdim + wG) * Tdim + t0 + 4 * tfh;
        #pragma unroll
        for (int c = 0; c < 3; ++c) {
            float4 o;
            o.x = vals[c*4 + 0] * inv[0];
            o.y = vals[c*4 + 1] * inv[1];
            o.z = vals[c*4 + 2] * inv[2];
            o.w = vals[c*4 + 3] * inv[3];
            *(float4*)(out + c*CS + ob) = o;
        }
    }
}

extern "C" void kernel_launch(void* const* d_in, const int* in_sizes, int n_in,
                              void* d_out, int out_size, void* d_ws, size_t ws_size,
                              hipStream_t stream) {
    const float* noisy    = (const float*)d_in[0];
    const float* guidance = (const float*)d_in[1];
    const float* est      = (const float*)d_in[2];
    const float* var      = (const float*)d_in[3];
    const float* sig      = (const float*)d_in[4];
    float* out = (float*)d_out;

    (void)in_sizes; (void)n_in; (void)out_size; (void)d_ws; (void)ws_size;

    (void)hipFuncSetAttribute(reinterpret_cast<const void*>(statden_kernel),
                              hipFuncAttributeMaxDynamicSharedMemorySize, SMEM_BYTES);

    dim3 grid(Wdim / TW, Hdim / TH, Tdim / TT);   // (16, 32, 4)
    statden_kernel<<<grid, NTHREADS, SMEM_BYTES, stream>>>(noisy, guidance, est, var, sig, out);
}

// Round 5
// 495.998 us; speedup vs baseline: 1.1711x; 1.1711x over previous
//
#include <hip/hip_runtime.h>

// ---- problem constants ----
#define SRAD 3
#define TRAD 1
#define Hdim 256
#define Wdim 256
#define Tdim 32
#define CS (Hdim*Wdim*Tdim)

// ---- tiling ----
#define TH 8
#define TW 16
#define TT 8
#define HS (TH + 2*SRAD)      // 14
#define WS (TW + 2*SRAD)      // 22
#define TSZ (TT + 2*TRAD)     // 10 real t-px per row
#define RS 11                 // padded row stride (px) -> conflict-free banks
#define NROWS (HS*WS)         // 308
#define NPX (NROWS*TSZ)       // 3080 real px
#define NSLOT (NROWS*RS)      // 3388 padded slots
#define NTHREADS 1024
#define NSUB 4

// LDS planes (dword offsets), per px slot:
//   AG [NSLOT][4] : (g0,g1)(g2,g3)(g4,g5)(g6,g7)  fp16 pairs, sigma-scaled
//   EVN[NSLOT][4] : (e0,e1)(v0,v1)(e2,v2)(n0,n1)  fp16 pairs
//   X  [NSLOT][1] : (g8,n2)                        fp16 pair
#define EVN_OFF (4*NSLOT)     // 13552
#define X_OFF   (8*NSLOT)     // 27104
#define SMEM_BYTES (9*NSLOT*4) // 121,968 B (< 160 KiB)

typedef _Float16 half2_t __attribute__((ext_vector_type(2)));

#if defined(__has_builtin)
#if __has_builtin(__builtin_amdgcn_fdot2)
#define HAVE_FDOT2 1
#else
#define HAVE_FDOT2 0
#endif
#else
#define HAVE_FDOT2 0
#endif

static __device__ __forceinline__ unsigned pack_h2(float a, float b) {
    return __builtin_bit_cast(unsigned, __builtin_amdgcn_cvt_pkrtz(a, b));
}
static __device__ __forceinline__ half2_t h2(unsigned u) {
    return __builtin_bit_cast(half2_t, u);
}
static __device__ __forceinline__ float dacc(unsigned y, half2_t x, float acc) {
    half2_t d = h2(y) - x;
#if HAVE_FDOT2
    return __builtin_amdgcn_fdot2(d, d, acc, false);
#else
    float a = (float)d.x, b = (float)d.y;
    return __builtin_fmaf(a, a, __builtin_fmaf(b, b, acc));
#endif
}
// only low half (g8) contributes; high half carries n2
static __device__ __forceinline__ float dacc_lo(unsigned y, unsigned x, float acc) {
    half2_t d = h2(y) - h2(x);
    half2_t dm = h2(__builtin_bit_cast(unsigned, d) & 0xFFFFu);
#if HAVE_FDOT2
    return __builtin_amdgcn_fdot2(dm, dm, acc, false);
#else
    float a = (float)dm.x;
    return __builtin_fmaf(a, a, acc);
#endif
}

__global__ __launch_bounds__(NTHREADS, 4) void statden_kernel(
    const float* __restrict__ noisy, const float* __restrict__ guidance,
    const float* __restrict__ est, const float* __restrict__ var,
    const float* __restrict__ sigma_inv, float* __restrict__ out)
{
    extern __shared__ unsigned char smem[];
    unsigned* agP  = (unsigned*)smem;
    unsigned* evnP = agP + EVN_OFF;
    unsigned* xP   = agP + X_OFF;

    const int tid = threadIdx.x;
    const int pix = tid & 255;
    const int sub = tid >> 8;            // 4-way (dh,dw)-offset split (wave-uniform)
    const int h0 = blockIdx.y * TH;
    const int w0 = blockIdx.x * TW;
    const int t0 = blockIdx.z * TT;

    float sq[9];
    #pragma unroll
    for (int c = 0; c < 9; ++c) sq[c] = sqrtf(sigma_inv[c]);

    // ---- stage halo (zero-fill OOB == reference zero padding) ----
    for (int p = tid; p < NPX; p += NTHREADS) {
        int row = p / TSZ;
        int t   = p - row * TSZ;
        int pw  = row % WS;
        int ph  = row / WS;
        int h = h0 - SRAD + ph;
        int w = w0 - SRAD + pw;
        int tg = t0 - TRAD + t;
        bool ok = ((unsigned)h < (unsigned)Hdim) && ((unsigned)w < (unsigned)Wdim)
               && ((unsigned)tg < (unsigned)Tdim);
        int base = (h * Wdim + w) * Tdim + tg;

        float g[9];
        #pragma unroll
        for (int c = 0; c < 9; ++c) g[c] = ok ? guidance[c*CS + base] * sq[c] : 0.f;
        float e0 = ok ? est[0*CS + base] : 0.f;
        float e1 = ok ? est[1*CS + base] : 0.f;
        float e2 = ok ? est[2*CS + base] : 0.f;
        float v0 = ok ? var[0*CS + base] : 0.f;
        float v1 = ok ? var[1*CS + base] : 0.f;
        float v2 = ok ? var[2*CS + base] : 0.f;
        float n0 = ok ? noisy[0*CS + base] : 0.f;
        float n1 = ok ? noisy[1*CS + base] : 0.f;
        float n2 = ok ? noisy[2*CS + base] : 0.f;

        const int idx = row * RS + t;
        uint4 ag;
        ag.x = pack_h2(g[0], g[1]); ag.y = pack_h2(g[2], g[3]);
        ag.z = pack_h2(g[4], g[5]); ag.w = pack_h2(g[6], g[7]);
        *(uint4*)(agP + 4*idx) = ag;
        uint4 ev;
        ev.x = pack_h2(e0, e1); ev.y = pack_h2(v0, v1);
        ev.z = pack_h2(e2, v2); ev.w = pack_h2(n0, n1);
        *(uint4*)(evnP + 4*idx) = ev;
        xP[idx] = pack_h2(g[8], n2);
    }
    __syncthreads();

    // ---- per-thread output column: 4 consecutive t outputs ----
    const int tfh = pix & 1;
    const int ww  = (pix >> 1) & 15;
    const int hh  = pix >> 5;
    const int crow = (hh + SRAD) * WS + (ww + SRAD);
    const int cidx = crow * RS + 4 * tfh;   // window slot index (tp = 0..5)

    // center terms (output j lives at window t-pos j+1)
    half2_t agx[4][4];       // scaled guidance, centers
    unsigned cgx[4];         // (g8,n2) centers
    half2_t ex01[4];         // (e0,e1) center
    half2_t K01[4];          // gamma^2 * (v0,v1) center
    half2_t cx2m[4];         // (-e2, +v2) center
    const _Float16 G2h = (_Float16)(2.9146f * 2.9146f);
    const half2_t G2pk = { G2h, G2h };
    #pragma unroll
    for (int j = 0; j < 4; ++j) {
        const int ci = cidx + j + 1;
        uint4 cag = *(const uint4*)(agP + 4*ci);
        agx[j][0] = h2(cag.x); agx[j][1] = h2(cag.y);
        agx[j][2] = h2(cag.z); agx[j][3] = h2(cag.w);
        cgx[j] = xP[ci];
        uint4 cev = *(const uint4*)(evnP + 4*ci);
        ex01[j] = h2(cev.x);
        K01[j]  = G2pk * h2(cev.y);
        cx2m[j] = h2(cev.z ^ 0x00008000u);   // negate e2 (low half sign bit)
    }

    float nm0[4] = {0.f,0.f,0.f,0.f};
    float nm1[4] = {0.f,0.f,0.f,0.f};
    float nm2[4] = {0.f,0.f,0.f,0.f};
    float den[4] = {0.f,0.f,0.f,0.f};

    #pragma unroll 1
    for (int idx = sub; idx < 49; idx += NSUB) {
        const int dhp = idx / 7;
        const int dwp = idx - dhp * 7;
        const int nbase = cidx + ((dhp - SRAD) * WS + (dwp - SRAD)) * RS;

        #pragma unroll
        for (int tp = 0; tp < 6; ++tp) {
            const int ni = nbase + tp;
            const uint4 ag = *(const uint4*)(agP + 4*ni);
            const unsigned xv = xP[ni];
            const uint4 ev = *(const uint4*)(evnP + 4*ni);
            const half2_t ey01 = h2(ev.x);
            const half2_t vy01 = h2(ev.y);
            const half2_t ev2  = h2(ev.z);
            const half2_t ny01 = h2(ev.w);
            const _Float16 n2h = h2(xv).y;

            #pragma unroll
            for (int j = 0; j < 4; ++j) {
                if (tp - j < 0 || tp - j > 2) continue;   // dt window

                float dist = dacc(ag.x, agx[j][0], 0.f);
                dist = dacc(ag.y, agx[j][1], dist);
                dist = dacc(ag.z, agx[j][2], dist);
                dist = dacc(ag.w, agx[j][3], dist);
                dist = dacc_lo(xv, cgx[j], dist);
                const float wjf = __expf(-dist);

                // packed t-test: m = gamma^2*(vy+vx) - (ey-ex)^2 >= 0 per channel
                const half2_t de01 = ey01 - ex01[j];
                const half2_t t1   = G2pk * vy01 + K01[j];
                const half2_t m01  = t1 - de01 * de01;
                const half2_t s2   = ev2 + cx2m[j];      // (de2, vs2)
                const _Float16 m2  = G2h * s2.y - s2.x * s2.x;
                const bool member = (m01.x >= (_Float16)0) && (m01.y >= (_Float16)0)
                                 && (m2 >= (_Float16)0);
                const float wgt = member ? wjf : 0.f;

                nm0[j] = __builtin_fmaf(wgt, (float)ny01.x, nm0[j]);
                nm1[j] = __builtin_fmaf(wgt, (float)ny01.y, nm1[j]);
                nm2[j] = __builtin_fmaf(wgt, (float)n2h,    nm2[j]);
                den[j] += wgt;
            }
        }
    }

    // ---- combine 4 offset-split partials via LDS (bank-balanced) ----
    float vals[16];
    #pragma unroll
    for (int j = 0; j < 4; ++j) {
        vals[0*4+j] = nm0[j]; vals[1*4+j] = nm1[j];
        vals[2*4+j] = nm2[j]; vals[3*4+j] = den[j];
    }

    __syncthreads();
    float* red = (float*)smem;   // 3 * 256 * 16 * 4 B = 48 KB, reuse staged region
    if (sub != 0) {
        const int base = ((sub - 1) * 256 + pix) * 16;
        #pragma unroll
        for (int q = 0; q < 4; ++q) {
            float4 v;
            v.x = vals[4*q + 0]; v.y = vals[4*q + 1];
            v.z = vals[4*q + 2]; v.w = vals[4*q + 3];
            *(float4*)(red + base + 4 * (q ^ (pix & 3))) = v;
        }
    }
    __syncthreads();
    if (sub == 0) {
        #pragma unroll
        for (int s = 0; s < 3; ++s) {
            const int base = (s * 256 + pix) * 16;
            #pragma unroll
            for (int q = 0; q < 4; ++q) {
                float4 v = *(const float4*)(red + base + 4 * (q ^ (pix & 3)));
                vals[4*q + 0] += v.x; vals[4*q + 1] += v.y;
                vals[4*q + 2] += v.z; vals[4*q + 3] += v.w;
            }
        }
        float inv[4];
        #pragma unroll
        for (int j = 0; j < 4; ++j) inv[j] = 1.0f / (vals[12 + j] + 1e-10f);

        const int hG = h0 + hh, wG = w0 + ww;
        const int ob = (hG * Wdim + wG) * Tdim + t0 + 4 * tfh;
        #pragma unroll
        for (int c = 0; c < 3; ++c) {
            float4 o;
            o.x = vals[c*4 + 0] * inv[0];
            o.y = vals[c*4 + 1] * inv[1];
            o.z = vals[c*4 + 2] * inv[2];
            o.w = vals[c*4 + 3] * inv[3];
            *(float4*)(out + c*CS + ob) = o;
        }
    }
}

extern "C" void kernel_launch(void* const* d_in, const int* in_sizes, int n_in,
                              void* d_out, int out_size, void* d_ws, size_t ws_size,
                              hipStream_t stream) {
    const float* noisy    = (const float*)d_in[0];
    const float* guidance = (const float*)d_in[1];
    const float* est      = (const float*)d_in[2];
    const float* var      = (const float*)d_in[3];
    const float* sig      = (const float*)d_in[4];
    float* out = (float*)d_out;

    (void)in_sizes; (void)n_in; (void)out_size; (void)d_ws; (void)ws_size;

    (void)hipFuncSetAttribute(reinterpret_cast<const void*>(statden_kernel),
                              hipFuncAttributeMaxDynamicSharedMemorySize, SMEM_BYTES);

    dim3 grid(Wdim / TW, Hdim / TH, Tdim / TT);   // (16, 32, 4)
    statden_kernel<<<grid, NTHREADS, SMEM_BYTES, stream>>>(noisy, guidance, est, var, sig, out);
}

// Round 6
// 480.940 us; speedup vs baseline: 1.2078x; 1.0313x over previous
//
#include <hip/hip_runtime.h>

// ---- problem constants ----
#define SRAD 3
#define TRAD 1
#define Hdim 256
#define Wdim 256
#define Tdim 32
#define CS (Hdim*Wdim*Tdim)

// ---- tiling ----
#define TH 8
#define TW 16
#define TT 8
#define HS (TH + 2*SRAD)      // 14
#define WS (TW + 2*SRAD)      // 22
#define TSZ (TT + 2*TRAD)     // 10 real t-px per row
#define RS 11                 // padded row stride (px) -> conflict-free banks
#define NROWS (HS*WS)         // 308
#define NPX (NROWS*TSZ)       // 3080 real px
#define NSLOT (NROWS*RS)      // 3388 padded slots
#define NTHREADS 1024
#define NSUB 4

// LDS planes (dword offsets), per px slot:
//   AG [NSLOT][4] : (g0,g1)(g2,g3)(g4,g5)(g6,g7)  fp16 pairs, sigma*log2e-scaled
//   EVN[NSLOT][4] : (e0,e1)(v0,v1)(e2,v2)(n0,n1)  fp16 pairs
//   X  [NSLOT][1] : (g8,n2)                        fp16 pair
#define EVN_OFF (4*NSLOT)
#define X_OFF   (8*NSLOT)
#define SMEM_BYTES (9*NSLOT*4) // 121,968 B (< 160 KiB)

typedef _Float16 half2_t __attribute__((ext_vector_type(2)));

#if defined(__has_builtin)
#if __has_builtin(__builtin_amdgcn_fdot2)
#define HAVE_FDOT2 1
#else
#define HAVE_FDOT2 0
#endif
#if __has_builtin(__builtin_amdgcn_exp2f)
#define EXPW(x) __builtin_amdgcn_exp2f(x)
#define LOG2E_SC 1.4426950408889634f
#else
#define EXPW(x) __expf(x)
#define LOG2E_SC 1.0f
#endif
#if __has_builtin(__builtin_amdgcn_sched_barrier)
#define SB() __builtin_amdgcn_sched_barrier(0)
#else
#define SB()
#endif
#else
#define HAVE_FDOT2 0
#define EXPW(x) __expf(x)
#define LOG2E_SC 1.0f
#define SB()
#endif

static __device__ __forceinline__ unsigned pack_h2(float a, float b) {
    return __builtin_bit_cast(unsigned, __builtin_amdgcn_cvt_pkrtz(a, b));
}
static __device__ __forceinline__ half2_t h2(unsigned u) {
    return __builtin_bit_cast(half2_t, u);
}
static __device__ __forceinline__ float dacc(unsigned y, half2_t x, float acc) {
    half2_t d = h2(y) - x;
#if HAVE_FDOT2
    return __builtin_amdgcn_fdot2(d, d, acc, false);
#else
    float a = (float)d.x, b = (float)d.y;
    return __builtin_fmaf(a, a, __builtin_fmaf(b, b, acc));
#endif
}
// only low half (g8) contributes; fma_mix pattern, no mask needed
static __device__ __forceinline__ float dacc_lo(unsigned y, unsigned x, float acc) {
    half2_t d = h2(y) - h2(x);
    float dl = (float)d.x;
    return __builtin_fmaf(dl, dl, acc);
}
static __device__ __forceinline__ half2_t pkmin(half2_t a, half2_t b) {
#if defined(__has_builtin)
#if __has_builtin(__builtin_elementwise_min)
    return __builtin_elementwise_min(a, b);
#else
    half2_t r; r.x = a.x < b.x ? a.x : b.x; r.y = a.y < b.y ? a.y : b.y; return r;
#endif
#else
    half2_t r; r.x = a.x < b.x ? a.x : b.x; r.y = a.y < b.y ? a.y : b.y; return r;
#endif
}

__global__ __launch_bounds__(NTHREADS, 4) void statden_kernel(
    const float* __restrict__ noisy, const float* __restrict__ guidance,
    const float* __restrict__ est, const float* __restrict__ var,
    const float* __restrict__ sigma_inv, float* __restrict__ out)
{
    extern __shared__ unsigned char smem[];
    unsigned* agP  = (unsigned*)smem;
    unsigned* evnP = agP + EVN_OFF;
    unsigned* xP   = agP + X_OFF;

    const int tid = threadIdx.x;
    const int pix = tid & 255;
    const int sub = tid >> 8;            // 4-way (dh,dw)-offset split (wave-uniform)
    const int h0 = blockIdx.y * TH;
    const int w0 = blockIdx.x * TW;
    const int t0 = blockIdx.z * TT;

    float sq[9];
    #pragma unroll
    for (int c = 0; c < 9; ++c) sq[c] = sqrtf(sigma_inv[c] * LOG2E_SC);

    // ---- stage halo (zero-fill OOB == reference zero padding) ----
    for (int p = tid; p < NPX; p += NTHREADS) {
        int row = p / TSZ;
        int t   = p - row * TSZ;
        int pw  = row % WS;
        int ph  = row / WS;
        int h = h0 - SRAD + ph;
        int w = w0 - SRAD + pw;
        int tg = t0 - TRAD + t;
        bool ok = ((unsigned)h < (unsigned)Hdim) && ((unsigned)w < (unsigned)Wdim)
               && ((unsigned)tg < (unsigned)Tdim);
        int base = (h * Wdim + w) * Tdim + tg;

        float g[9];
        #pragma unroll
        for (int c = 0; c < 9; ++c) g[c] = ok ? guidance[c*CS + base] * sq[c] : 0.f;
        float e0 = ok ? est[0*CS + base] : 0.f;
        float e1 = ok ? est[1*CS + base] : 0.f;
        float e2 = ok ? est[2*CS + base] : 0.f;
        float v0 = ok ? var[0*CS + base] : 0.f;
        float v1 = ok ? var[1*CS + base] : 0.f;
        float v2 = ok ? var[2*CS + base] : 0.f;
        float n0 = ok ? noisy[0*CS + base] : 0.f;
        float n1 = ok ? noisy[1*CS + base] : 0.f;
        float n2 = ok ? noisy[2*CS + base] : 0.f;

        const int idx = row * RS + t;
        uint4 ag;
        ag.x = pack_h2(g[0], g[1]); ag.y = pack_h2(g[2], g[3]);
        ag.z = pack_h2(g[4], g[5]); ag.w = pack_h2(g[6], g[7]);
        *(uint4*)(agP + 4*idx) = ag;
        uint4 ev;
        ev.x = pack_h2(e0, e1); ev.y = pack_h2(v0, v1);
        ev.z = pack_h2(e2, v2); ev.w = pack_h2(n0, n1);
        *(uint4*)(evnP + 4*idx) = ev;
        xP[idx] = pack_h2(g[8], n2);
    }
    __syncthreads();

    // ---- per-thread output column: 4 consecutive t outputs ----
    const int tfh = pix & 1;
    const int ww  = (pix >> 1) & 15;
    const int hh  = pix >> 5;
    const int crow = (hh + SRAD) * WS + (ww + SRAD);
    const int cidx = crow * RS + 4 * tfh;   // window slot index (tp = 0..5)

    // center terms (output j lives at window t-pos j+1)
    half2_t agx[4][4];
    unsigned cgx[4];
    half2_t ex01[4];
    half2_t K01[4];          // gamma^2 * (v0,v1) center
    half2_t cx2m[4];         // (-e2, +v2) center
    const _Float16 G2h = (_Float16)(2.9146f * 2.9146f);
    const half2_t G2pk = { G2h, G2h };
    #pragma unroll
    for (int j = 0; j < 4; ++j) {
        const int ci = cidx + j + 1;
        uint4 cag = *(const uint4*)(agP + 4*ci);
        agx[j][0] = h2(cag.x); agx[j][1] = h2(cag.y);
        agx[j][2] = h2(cag.z); agx[j][3] = h2(cag.w);
        cgx[j] = xP[ci];
        uint4 cev = *(const uint4*)(evnP + 4*ci);
        ex01[j] = h2(cev.x);
        K01[j]  = G2pk * h2(cev.y);
        cx2m[j] = h2(cev.z ^ 0x00008000u);   // negate e2
    }

    float nm0[4] = {0.f,0.f,0.f,0.f};
    float nm1[4] = {0.f,0.f,0.f,0.f};
    float nm2[4] = {0.f,0.f,0.f,0.f};
    float den[4] = {0.f,0.f,0.f,0.f};

#define EVALJ(AG, EV, XV, j) do {                                        \
    float dist = dacc(AG.x, agx[j][0], 0.f);                             \
    dist = dacc(AG.y, agx[j][1], dist);                                  \
    dist = dacc(AG.z, agx[j][2], dist);                                  \
    dist = dacc(AG.w, agx[j][3], dist);                                  \
    dist = dacc_lo(XV, cgx[j], dist);                                    \
    const float wjf = EXPW(-dist);                                       \
    const half2_t de01 = h2(EV.x) - ex01[j];                             \
    const half2_t t1   = G2pk * h2(EV.y) + K01[j];                       \
    const half2_t m01  = t1 - de01 * de01;                               \
    const half2_t s2   = h2(EV.z) + cx2m[j];                             \
    const _Float16 m2v = G2h * s2.y - s2.x * s2.x;                       \
    const half2_t m2p  = { m2v, m2v };                                   \
    const half2_t mn   = pkmin(m01, m2p);                                \
    const unsigned mb  = __builtin_bit_cast(unsigned, mn);               \
    const float wgt = ((mb & 0x80008000u) == 0u) ? wjf : 0.f;            \
    nm0[j] = __builtin_fmaf(wgt, (float)h2(EV.w).x, nm0[j]);             \
    nm1[j] = __builtin_fmaf(wgt, (float)h2(EV.w).y, nm1[j]);             \
    nm2[j] = __builtin_fmaf(wgt, (float)h2(XV).y,  nm2[j]);              \
    den[j] += wgt;                                                       \
} while (0)

#define LW(T) do {                                                       \
    a##T = *(const uint4*)(agB + 4*(T));                                 \
    e##T = *(const uint4*)(evB + 4*(T));                                 \
    q##T = xB[(T)];                                                      \
} while (0)

    #pragma unroll 1
    for (int it = sub; it < 49; it += NSUB) {
        const int dhp = it / 7;
        const int dwp = it - dhp * 7;
        const int nbase = cidx + ((dhp - SRAD) * WS + (dwp - SRAD)) * RS;
        const unsigned* __restrict__ agB = agP + 4*nbase;
        const unsigned* __restrict__ evB = evnP + 4*nbase;
        const unsigned* __restrict__ xB  = xP + nbase;

        uint4 a0, a1, a2, a3, a4, a5;
        uint4 e0, e1, e2, e3, e4, e5;
        unsigned q0, q1, q2, q3, q4, q5;

        // software pipeline: 3 windows in flight, compute hides LDS latency
        LW(0); LW(1); LW(2);
        SB();
        EVALJ(a0, e0, q0, 0);
        LW(3);
        SB();
        EVALJ(a1, e1, q1, 0); EVALJ(a1, e1, q1, 1);
        LW(4);
        SB();
        EVALJ(a2, e2, q2, 0); EVALJ(a2, e2, q2, 1); EVALJ(a2, e2, q2, 2);
        LW(5);
        SB();
        EVALJ(a3, e3, q3, 1); EVALJ(a3, e3, q3, 2); EVALJ(a3, e3, q3, 3);
        EVALJ(a4, e4, q4, 2); EVALJ(a4, e4, q4, 3);
        EVALJ(a5, e5, q5, 3);
    }

    // ---- combine 4 offset-split partials via LDS (bank-balanced) ----
    float vals[16];
    #pragma unroll
    for (int j = 0; j < 4; ++j) {
        vals[0*4+j] = nm0[j]; vals[1*4+j] = nm1[j];
        vals[2*4+j] = nm2[j]; vals[3*4+j] = den[j];
    }

    __syncthreads();
    float* red = (float*)smem;   // 48 KB, reuse staged region
    if (sub != 0) {
        const int base = ((sub - 1) * 256 + pix) * 16;
        #pragma unroll
        for (int q = 0; q < 4; ++q) {
            float4 v;
            v.x = vals[4*q + 0]; v.y = vals[4*q + 1];
            v.z = vals[4*q + 2]; v.w = vals[4*q + 3];
            *(float4*)(red + base + 4 * (q ^ (pix & 3))) = v;
        }
    }
    __syncthreads();
    if (sub == 0) {
        #pragma unroll
        for (int s = 0; s < 3; ++s) {
            const int base = (s * 256 + pix) * 16;
            #pragma unroll
            for (int q = 0; q < 4; ++q) {
                float4 v = *(const float4*)(red + base + 4 * (q ^ (pix & 3)));
                vals[4*q + 0] += v.x; vals[4*q + 1] += v.y;
                vals[4*q + 2] += v.z; vals[4*q + 3] += v.w;
            }
        }
        float inv[4];
        #pragma unroll
        for (int j = 0; j < 4; ++j) inv[j] = 1.0f / (vals[12 + j] + 1e-10f);

        const int hG = h0 + hh, wG = w0 + ww;
        const int ob = (hG * Wdim + wG) * Tdim + t0 + 4 * tfh;
        #pragma unroll
        for (int c = 0; c < 3; ++c) {
            float4 o;
            o.x = vals[c*4 + 0] * inv[0];
            o.y = vals[c*4 + 1] * inv[1];
            o.z = vals[c*4 + 2] * inv[2];
            o.w = vals[c*4 + 3] * inv[3];
            *(float4*)(out + c*CS + ob) = o;
        }
    }
}

extern "C" void kernel_launch(void* const* d_in, const int* in_sizes, int n_in,
                              void* d_out, int out_size, void* d_ws, size_t ws_size,
                              hipStream_t stream) {
    const float* noisy    = (const float*)d_in[0];
    const float* guidance = (const float*)d_in[1];
    const float* est      = (const float*)d_in[2];
    const float* var      = (const float*)d_in[3];
    const float* sig      = (const float*)d_in[4];
    float* out = (float*)d_out;

    (void)in_sizes; (void)n_in; (void)out_size; (void)d_ws; (void)ws_size;

    (void)hipFuncSetAttribute(reinterpret_cast<const void*>(statden_kernel),
                              hipFuncAttributeMaxDynamicSharedMemorySize, SMEM_BYTES);

    dim3 grid(Wdim / TW, Hdim / TH, Tdim / TT);   // (16, 32, 4)
    statden_kernel<<<grid, NTHREADS, SMEM_BYTES, stream>>>(noisy, guidance, est, var, sig, out);
}

// Round 7
// 413.820 us; speedup vs baseline: 1.4036x; 1.1622x over previous
//
#include <hip/hip_runtime.h>

// ---- problem constants ----
#define SRAD 3
#define TRAD 1
#define Hdim 256
#define Wdim 256
#define Tdim 32
#define CS (Hdim*Wdim*Tdim)

// ---- tiling ----
#define TH 8
#define TW 16
#define TT 8
#define HS (TH + 2*SRAD)      // 14
#define WS (TW + 2*SRAD)      // 22
#define TSZ (TT + 2*TRAD)     // 10 real t-px per row
#define RS 11                 // padded row stride (px) -> conflict-free banks
#define NROWS (HS*WS)         // 308
#define NPX (NROWS*TSZ)       // 3080 real px
#define NSLOT (NROWS*RS)      // 3388 padded slots
#define NTHREADS 1024
#define NSUB 4

// LDS planes (dword offsets), per px slot:
//   AG [NSLOT][4] : (g0,g1)(g2,g3)(g4,g5)(g6,g7)  fp16 pairs, sqrt(sigma*log2e)-scaled
//   EVN[NSLOT][4] : (e0',e1')(v0,v1)(e2',v2)(n0,n1) fp16 pairs, e' = e/gamma
//   X2 [NSLOT][2] : (g8,n2) fp16 pair | S f32  (S = sum of scaled-g^2, dot2-chain order)
#define EVN_OFF (4*NSLOT)
#define X2_OFF  (8*NSLOT)
#define SMEM_BYTES (10*NSLOT*4) // 135,520 B (< 160 KiB)

typedef _Float16 half2_t __attribute__((ext_vector_type(2)));

#if defined(__has_builtin)
#if __has_builtin(__builtin_amdgcn_fdot2)
#define HAVE_FDOT2 1
#else
#define HAVE_FDOT2 0
#endif
#if __has_builtin(__builtin_amdgcn_exp2f)
#define EXPW(x) __builtin_amdgcn_exp2f(x)
#define LOG2E_SC 1.4426950408889634f
#else
#define EXPW(x) __expf(x)
#define LOG2E_SC 1.0f
#endif
#if __has_builtin(__builtin_elementwise_fma)
#define PKFMA(a, b, c) __builtin_elementwise_fma((a), (b), (c))
#else
#define PKFMA(a, b, c) ((a) * (b) + (c))
#endif
#if __has_builtin(__builtin_fminf16)
#define HMIN(a, b) __builtin_fminf16((a), (b))
#else
#define HMIN(a, b) ((a) < (b) ? (a) : (b))
#endif
#else
#define HAVE_FDOT2 0
#define EXPW(x) __expf(x)
#define LOG2E_SC 1.0f
#define PKFMA(a, b, c) ((a) * (b) + (c))
#define HMIN(a, b) ((a) < (b) ? (a) : (b))
#endif

#define INVG 0.343100187f   // 1 / 2.9146

static __device__ __forceinline__ unsigned pack_h2(float a, float b) {
    return __builtin_bit_cast(unsigned, __builtin_amdgcn_cvt_pkrtz(a, b));
}
static __device__ __forceinline__ half2_t h2(unsigned u) {
    return __builtin_bit_cast(half2_t, u);
}
// dot-product accumulate: acc += y . x  (2 fp16 lanes)
static __device__ __forceinline__ float dot2p(unsigned y, half2_t x, float acc) {
#if HAVE_FDOT2
    return __builtin_amdgcn_fdot2(h2(y), x, acc, false);
#else
    half2_t yv = h2(y);
    return __builtin_fmaf((float)yv.x, (float)x.x,
           __builtin_fmaf((float)yv.y, (float)x.y, acc));
#endif
}
static __device__ __forceinline__ float dot2s(unsigned y, unsigned x, float acc) {
    return dot2p(y, h2(x), acc);
}

__global__ __attribute__((amdgpu_flat_work_group_size(NTHREADS, NTHREADS),
                          amdgpu_waves_per_eu(4, 4)))
void statden_kernel(
    const float* __restrict__ noisy, const float* __restrict__ guidance,
    const float* __restrict__ est, const float* __restrict__ var,
    const float* __restrict__ sigma_inv, float* __restrict__ out)
{
    extern __shared__ unsigned char smem[];
    unsigned* agP  = (unsigned*)smem;
    unsigned* evnP = agP + EVN_OFF;
    unsigned* x2P  = agP + X2_OFF;

    const int tid = threadIdx.x;
    const int pix = tid & 255;
    const int sub = tid >> 8;            // 4-way (dh,dw)-offset split (wave-uniform)
    const int h0 = blockIdx.y * TH;
    const int w0 = blockIdx.x * TW;
    const int t0 = blockIdx.z * TT;

    float sq[9];
    #pragma unroll
    for (int c = 0; c < 9; ++c) sq[c] = sqrtf(sigma_inv[c] * LOG2E_SC);

    // ---- stage halo (zero-fill OOB == reference zero padding) ----
    for (int p = tid; p < NPX; p += NTHREADS) {
        int row = p / TSZ;
        int t   = p - row * TSZ;
        int pw  = row % WS;
        int ph  = row / WS;
        int h = h0 - SRAD + ph;
        int w = w0 - SRAD + pw;
        int tg = t0 - TRAD + t;
        bool ok = ((unsigned)h < (unsigned)Hdim) && ((unsigned)w < (unsigned)Wdim)
               && ((unsigned)tg < (unsigned)Tdim);
        int base = (h * Wdim + w) * Tdim + tg;

        float g[9];
        #pragma unroll
        for (int c = 0; c < 9; ++c) g[c] = ok ? guidance[c*CS + base] * sq[c] : 0.f;
        float e0 = ok ? est[0*CS + base] * INVG : 0.f;
        float e1 = ok ? est[1*CS + base] * INVG : 0.f;
        float e2 = ok ? est[2*CS + base] * INVG : 0.f;
        float v0 = ok ? var[0*CS + base] : 0.f;
        float v1 = ok ? var[1*CS + base] : 0.f;
        float v2 = ok ? var[2*CS + base] : 0.f;
        float n0 = ok ? noisy[0*CS + base] : 0.f;
        float n1 = ok ? noisy[1*CS + base] : 0.f;
        float n2 = ok ? noisy[2*CS + base] : 0.f;

        const int idx = row * RS + t;
        uint4 ag;
        ag.x = pack_h2(g[0], g[1]); ag.y = pack_h2(g[2], g[3]);
        ag.z = pack_h2(g[4], g[5]); ag.w = pack_h2(g[6], g[7]);
        *(uint4*)(agP + 4*idx) = ag;
        uint4 ev;
        ev.x = pack_h2(e0, e1); ev.y = pack_h2(v0, v1);
        ev.z = pack_h2(e2, v2); ev.w = pack_h2(n0, n1);
        *(uint4*)(evnP + 4*idx) = ev;
        unsigned xq = pack_h2(g[8], n2);
        // S from PACKED values, same chain order as eval-time dot -> center dist == 0
        half2_t x8 = h2(xq);
        float S = __builtin_fmaf((float)x8.x, (float)x8.x, 0.f);
        S = dot2s(ag.x, ag.x, S);
        S = dot2s(ag.y, ag.y, S);
        S = dot2s(ag.z, ag.z, S);
        S = dot2s(ag.w, ag.w, S);
        uint2 x2; x2.x = xq; x2.y = __builtin_bit_cast(unsigned, S);
        *(uint2*)(x2P + 2*idx) = x2;
    }
    __syncthreads();

    // ---- per-thread output column: 4 consecutive t outputs ----
    const int tfh = pix & 1;
    const int ww  = (pix >> 1) & 15;
    const int hh  = pix >> 5;
    const int crow = (hh + SRAD) * WS + (ww + SRAD);
    const int cidx = crow * RS + 4 * tfh;   // window slot index (tp = 0..5)

    // center terms (output j lives at window t-pos j+1)
    half2_t agx[4][4];
    float   cgxf[4];         // (float) scaled g8 center
    float   Sx[4];
    half2_t ex01[4];         // (e0',e1') center
    half2_t vx01[4];         // (v0,v1) center
    half2_t cx2m[4];         // (-e2', +v2) center
    #pragma unroll
    for (int j = 0; j < 4; ++j) {
        const int ci = cidx + j + 1;
        uint4 cag = *(const uint4*)(agP + 4*ci);
        agx[j][0] = h2(cag.x); agx[j][1] = h2(cag.y);
        agx[j][2] = h2(cag.z); agx[j][3] = h2(cag.w);
        uint2 cx2 = *(const uint2*)(x2P + 2*ci);
        cgxf[j] = (float)h2(cx2.x).x;
        Sx[j]   = __builtin_bit_cast(float, cx2.y);
        uint4 cev = *(const uint4*)(evnP + 4*ci);
        ex01[j] = h2(cev.x);
        vx01[j] = h2(cev.y);
        cx2m[j] = h2(cev.z ^ 0x00008000u);   // negate e2'
    }

    float nm0[4] = {0.f,0.f,0.f,0.f};
    float nm1[4] = {0.f,0.f,0.f,0.f};
    float nm2[4] = {0.f,0.f,0.f,0.f};
    float den[4] = {0.f,0.f,0.f,0.f};

#define EVALJ(A, E, QQ, SY, j) do {                                      \
    float dot = __builtin_fmaf((float)h2(QQ).x, cgxf[j], 0.f);           \
    dot = dot2p(A.x, agx[j][0], dot);                                    \
    dot = dot2p(A.y, agx[j][1], dot);                                    \
    dot = dot2p(A.z, agx[j][2], dot);                                    \
    dot = dot2p(A.w, agx[j][3], dot);                                    \
    const float dist = __builtin_fmaf(dot, -2.0f, SY + Sx[j]);           \
    const float wjf = EXPW(-dist);                                       \
    const half2_t de01 = h2(E.x) - ex01[j];                              \
    const half2_t vs01 = h2(E.y) + vx01[j];                              \
    const half2_t m01  = PKFMA(-de01, de01, vs01);                       \
    const half2_t s2   = h2(E.z) + cx2m[j];                              \
    const _Float16 m2v = __builtin_fmaf16(-s2.x, s2.x, s2.y);            \
    const _Float16 mn  = HMIN(HMIN(m01.x, m01.y), m2v);                  \
    const float wgt = (mn >= (_Float16)0) ? wjf : 0.f;                   \
    nm0[j] = __builtin_fmaf(wgt, (float)h2(E.w).x, nm0[j]);              \
    nm1[j] = __builtin_fmaf(wgt, (float)h2(E.w).y, nm1[j]);              \
    nm2[j] = __builtin_fmaf(wgt, (float)h2(QQ).y,  nm2[j]);              \
    den[j] += wgt;                                                       \
} while (0)

    #pragma unroll 1
    for (int it = sub; it < 49; it += NSUB) {
        const int dhp = it / 7;
        const int dwp = it - dhp * 7;
        const int nbase = cidx + ((dhp - SRAD) * WS + (dwp - SRAD)) * RS;
        const unsigned* __restrict__ agB = agP + 4*nbase;
        const unsigned* __restrict__ evB = evnP + 4*nbase;
        const unsigned* __restrict__ x2B = x2P + 2*nbase;

        uint4 a[6]; uint4 e[6]; unsigned q[6]; float Sy[6];
        #pragma unroll
        for (int tp = 0; tp < 6; ++tp) {
            a[tp] = *(const uint4*)(agB + 4*tp);
            e[tp] = *(const uint4*)(evB + 4*tp);
            uint2 x2 = *(const uint2*)(x2B + 2*tp);
            q[tp] = x2.x;
            Sy[tp] = __builtin_bit_cast(float, x2.y);
        }

        EVALJ(a[0], e[0], q[0], Sy[0], 0);
        EVALJ(a[1], e[1], q[1], Sy[1], 0); EVALJ(a[1], e[1], q[1], Sy[1], 1);
        EVALJ(a[2], e[2], q[2], Sy[2], 0); EVALJ(a[2], e[2], q[2], Sy[2], 1); EVALJ(a[2], e[2], q[2], Sy[2], 2);
        EVALJ(a[3], e[3], q[3], Sy[3], 1); EVALJ(a[3], e[3], q[3], Sy[3], 2); EVALJ(a[3], e[3], q[3], Sy[3], 3);
        EVALJ(a[4], e[4], q[4], Sy[4], 2); EVALJ(a[4], e[4], q[4], Sy[4], 3);
        EVALJ(a[5], e[5], q[5], Sy[5], 3);
    }

    // ---- combine 4 offset-split partials via LDS (bank-balanced) ----
    float vals[16];
    #pragma unroll
    for (int j = 0; j < 4; ++j) {
        vals[0*4+j] = nm0[j]; vals[1*4+j] = nm1[j];
        vals[2*4+j] = nm2[j]; vals[3*4+j] = den[j];
    }

    __syncthreads();
    float* red = (float*)smem;   // 48 KB, reuse staged region
    if (sub != 0) {
        const int base = ((sub - 1) * 256 + pix) * 16;
        #pragma unroll
        for (int q = 0; q < 4; ++q) {
            float4 v;
            v.x = vals[4*q + 0]; v.y = vals[4*q + 1];
            v.z = vals[4*q + 2]; v.w = vals[4*q + 3];
            *(float4*)(red + base + 4 * (q ^ (pix & 3))) = v;
        }
    }
    __syncthreads();
    if (sub == 0) {
        #pragma unroll
        for (int s = 0; s < 3; ++s) {
            const int base = (s * 256 + pix) * 16;
            #pragma unroll
            for (int q = 0; q < 4; ++q) {
                float4 v = *(const float4*)(red + base + 4 * (q ^ (pix & 3)));
                vals[4*q + 0] += v.x; vals[4*q + 1] += v.y;
                vals[4*q + 2] += v.z; vals[4*q + 3] += v.w;
            }
        }
        float inv[4];
        #pragma unroll
        for (int j = 0; j < 4; ++j) inv[j] = 1.0f / (vals[12 + j] + 1e-10f);

        const int hG = h0 + hh, wG = w0 + ww;
        const int ob = (hG * Wdim + wG) * Tdim + t0 + 4 * tfh;
        #pragma unroll
        for (int c = 0; c < 3; ++c) {
            float4 o;
            o.x = vals[c*4 + 0] * inv[0];
            o.y = vals[c*4 + 1] * inv[1];
            o.z = vals[c*4 + 2] * inv[2];
            o.w = vals[c*4 + 3] * inv[3];
            *(float4*)(out + c*CS + ob) = o;
        }
    }
}

extern "C" void kernel_launch(void* const* d_in, const int* in_sizes, int n_in,
                              void* d_out, int out_size, void* d_ws, size_t ws_size,
                              hipStream_t stream) {
    const float* noisy    = (const float*)d_in[0];
    const float* guidance = (const float*)d_in[1];
    const float* est      = (const float*)d_in[2];
    const float* var      = (const float*)d_in[3];
    const float* sig      = (const float*)d_in[4];
    float* out = (float*)d_out;

    (void)in_sizes; (void)n_in; (void)out_size; (void)d_ws; (void)ws_size;

    (void)hipFuncSetAttribute(reinterpret_cast<const void*>(statden_kernel),
                              hipFuncAttributeMaxDynamicSharedMemorySize, SMEM_BYTES);

    dim3 grid(Wdim / TW, Hdim / TH, Tdim / TT);   // (16, 32, 4)
    statden_kernel<<<grid, NTHREADS, SMEM_BYTES, stream>>>(noisy, guidance, est, var, sig, out);
}